// Round 8
// baseline (429.535 us; speedup 1.0000x reference)
//
#include <hip/hip_runtime.h>
#include <math.h>

#define IN_F    1024
#define NB      256
#define NL      17
#define BATCH_N 16384
#define RPW     2              // rows per wave (= per 64-thread block)
#define NTRP    (NL * 4)       // trace partial slots (17 blocks x 4 waves)

typedef float v4f __attribute__((ext_vector_type(4)));

// ---------------------------------------------------------------------------
// Kernel 1: expm of 4352 4x4 matrices (f32 scaling-and-squaring + Taylor-9).
// Per-wave trace partials to fixed slots (no atomic, no memset needed).
// ---------------------------------------------------------------------------
__global__ __launch_bounds__(256) void expm_kernel(const float* __restrict__ vs,
                                                   float* __restrict__ E,
                                                   float* __restrict__ tr_part) {
    const int m = blockIdx.x * 256 + threadIdx.x;   // 0..4351 (grid exact)
    const float* v = vs + (size_t)m * 16;
    float A[16], X[16], P[16], T[16];
    #pragma unroll
    for (int i = 0; i < 16; ++i) A[i] = v[i];
    const float tr = A[0] + A[5] + A[10] + A[15];

    float n1 = 0.0f;
    #pragma unroll
    for (int j = 0; j < 4; ++j) {
        float c = fabsf(A[j]) + fabsf(A[4 + j]) + fabsf(A[8 + j]) + fabsf(A[12 + j]);
        n1 = fmaxf(n1, c);
    }
    int s = 0;
    while (n1 > 0.25f && s < 30) { n1 *= 0.5f; ++s; }
    const float sc = __int_as_float((127 - s) << 23);   // 2^-s
    #pragma unroll
    for (int i = 0; i < 16; ++i) { A[i] *= sc; P[i] = A[i]; X[i] = A[i]; }
    X[0] += 1.0f; X[5] += 1.0f; X[10] += 1.0f; X[15] += 1.0f;

    #pragma unroll 1
    for (int k = 2; k <= 9; ++k) {
        const float invk = 1.0f / (float)k;
        #pragma unroll
        for (int i = 0; i < 4; ++i)
            #pragma unroll
            for (int j = 0; j < 4; ++j)
                T[i * 4 + j] = P[i * 4 + 0] * A[0 + j] + P[i * 4 + 1] * A[4 + j] +
                               P[i * 4 + 2] * A[8 + j] + P[i * 4 + 3] * A[12 + j];
        #pragma unroll
        for (int i = 0; i < 16; ++i) { P[i] = T[i] * invk; X[i] += P[i]; }
    }
    #pragma unroll 1
    for (int q = 0; q < s; ++q) {
        #pragma unroll
        for (int i = 0; i < 4; ++i)
            #pragma unroll
            for (int j = 0; j < 4; ++j)
                T[i * 4 + j] = X[i * 4 + 0] * X[0 + j] + X[i * 4 + 1] * X[4 + j] +
                               X[i * 4 + 2] * X[8 + j] + X[i * 4 + 3] * X[12 + j];
        #pragma unroll
        for (int i = 0; i < 16; ++i) X[i] = T[i];
    }
    float* e = E + (size_t)m * 16;
    #pragma unroll
    for (int i = 0; i < 16; ++i) e[i] = X[i];

    float tf = tr;
    #pragma unroll
    for (int off = 32; off > 0; off >>= 1) tf += __shfl_down(tf, off);
    if ((threadIdx.x & 63) == 0)
        tr_part[blockIdx.x * 4 + (threadIdx.x >> 6)] = tf;
}

// ---------------------------------------------------------------------------
// Kernel 2: wave-autonomous fused flow. One 64-thread block = one wave owning
// RPW=2 full rows. Lane owns 16 consecutive features = 4 whole 4x4 blocks, so
// the permutation gather is wave-private LDS: NO __syncthreads anywhere.
// Logdet: per-element ratio z/(2s)+1 in (0.5,1.5) -> product of 16 can never
// overflow/underflow f32 -> ONE log2 per row-layer.
// ---------------------------------------------------------------------------
__global__ __launch_bounds__(64, 4) void flow_kernel(const float* __restrict__ data,
                                                     const float* __restrict__ E,
                                                     const float* __restrict__ bs,
                                                     const int* __restrict__ idxs,
                                                     const float* __restrict__ tr_part,
                                                     float* __restrict__ out) {
    __shared__ float buf[RPW][IN_F];   // 8 KB, private to this wave
    const int lane = threadIdx.x;      // 0..63
    const int row0 = blockIdx.x * RPW;
    const int f0 = lane * 16;          // my 16 features; my blocks = 4*lane..4*lane+3

    v4f z[RPW][4];
    #pragma unroll
    for (int r = 0; r < RPW; ++r)
        #pragma unroll
        for (int g = 0; g < 4; ++g)
            z[r][g] = *(const v4f*)(data + (size_t)(row0 + r) * IN_F + f0 + 4 * g);

    float ld2[RPW];
    #pragma unroll
    for (int r = 0; r < RPW; ++r) ld2[r] = 0.0f;

    #pragma unroll 1
    for (int l = 0; l < NL; ++l) {
        if (l > 0) {
            // bent identity + logdet via bounded ratios:
            //   inv = rsqrt(z^2+1); sq = (z^2+1)*inv = sqrt(z^2+1)
            //   ratio = 0.5*z*inv + 1 = z/(2s)+1  in (0.5, 1.5)
            //   z' = 0.5*sq + z - 0.5
            #pragma unroll
            for (int r = 0; r < RPW; ++r) {
                v4f rat[4];
                #pragma unroll
                for (int g = 0; g < 4; ++g) {
                    const v4f zz = z[r][g];
                    const v4f q = zz * zz + 1.0f;
                    v4f inv;
                    inv.x = rsqrtf(q.x); inv.y = rsqrtf(q.y);
                    inv.z = rsqrtf(q.z); inv.w = rsqrtf(q.w);
                    const v4f sq = q * inv;                 // sqrt(z^2+1)
                    rat[g] = (0.5f * zz) * inv + 1.0f;      // bounded (0.5,1.5)
                    z[r][g] = (0.5f * sq + zz) - 0.5f;
                }
                const v4f p01 = rat[0] * rat[1];
                const v4f p23 = rat[2] * rat[3];
                const v4f pp = p01 * p23;
                ld2[r] += __log2f((pp.x * pp.y) * (pp.z * pp.w));
            }
        }

        // block-diag matvec + bias, staged to wave-private LDS.
        // My 4 E-blocks are contiguous: 64 floats at E + (l*NB + 4*lane)*16.
        const float* ep = E + ((size_t)l * NB + 4 * lane) * 16;
        const float* bp = bs + (size_t)l * IN_F + f0;
        #pragma unroll
        for (int b = 0; b < 4; ++b) {
            const v4f e0 = *(const v4f*)(ep + b * 16 + 0);
            const v4f e1 = *(const v4f*)(ep + b * 16 + 4);
            const v4f e2 = *(const v4f*)(ep + b * 16 + 8);
            const v4f e3 = *(const v4f*)(ep + b * 16 + 12);
            const v4f bb = *(const v4f*)(bp + 4 * b);
            #pragma unroll
            for (int r = 0; r < RPW; ++r) {
                const v4f zz = z[r][b];
                v4f y = bb;
                y += zz.x * e0;
                y += zz.y * e1;
                y += zz.z * e2;
                y += zz.w * e3;
                *(v4f*)(&buf[r][f0 + 4 * b]) = y;
            }
        }
        __builtin_amdgcn_wave_barrier();   // compiler fence: writes before reads

        // permutation gather (same idx for both rows)
        const int* ip = idxs + (size_t)l * IN_F + f0;
        #pragma unroll
        for (int g = 0; g < 4; ++g) {
            const int4 id = *(const int4*)(ip + 4 * g);
            #pragma unroll
            for (int r = 0; r < RPW; ++r) {
                v4f zn;
                zn.x = buf[r][id.x];
                zn.y = buf[r][id.y];
                zn.z = buf[r][id.z];
                zn.w = buf[r][id.w];
                z[r][g] = zn;
            }
        }
        __builtin_amdgcn_wave_barrier();   // fence before next layer's writes
    }

    // outputs
    float* out_z = out;
    float* out_ld = out + (size_t)BATCH_N * IN_F;
    #pragma unroll
    for (int r = 0; r < RPW; ++r)
        #pragma unroll
        for (int g = 0; g < 4; ++g)
            *(v4f*)(out_z + (size_t)(row0 + r) * IN_F + f0 + 4 * g) = z[r][g];

    // trace total (17 float4 = 68 partials, L2-resident)
    float trs = 0.0f;
    const v4f* tp = (const v4f*)tr_part;
    #pragma unroll
    for (int i = 0; i < NL; ++i) {
        const v4f tv = tp[i];
        trs += (tv.x + tv.y) + (tv.z + tv.w);
    }

    // per-row logdet: in-wave reduction, scale log2 -> ln at the end
    #pragma unroll
    for (int r = 0; r < RPW; ++r) {
        float p = ld2[r];
        #pragma unroll
        for (int off = 32; off > 0; off >>= 1) p += __shfl_down(p, off);
        if (lane == 0)
            out_ld[row0 + r] = -trs - 0.6931471805599453f * p;
    }
}

// ---------------------------------------------------------------------------
extern "C" void kernel_launch(void* const* d_in, const int* in_sizes, int n_in,
                              void* d_out, int out_size, void* d_ws, size_t ws_size,
                              hipStream_t stream) {
    const float* data = (const float*)d_in[0];
    const float* vs   = (const float*)d_in[1];
    const float* bs   = (const float*)d_in[2];
    const int*   idxs = (const int*)d_in[3];

    float* ws      = (float*)d_ws;
    float* tr_part = ws;          // NTRP floats (all slots written by expm)
    float* E       = ws + 128;    // 17*256*16 floats = 272 KB

    expm_kernel<<<NL, 256, 0, stream>>>(vs, E, tr_part);
    flow_kernel<<<BATCH_N / RPW, 64, 0, stream>>>(data, E, bs, idxs, tr_part, (float*)d_out);
}

// Round 13
// 233.775 us; speedup vs baseline: 1.8374x; 1.8374x over previous
//
#include <hip/hip_runtime.h>
#include <math.h>

#define IN_F    1024
#define NB      256
#define NL      17
#define BATCH_N 16384
#define RPB     8              // rows per 256-thread block
#define NTRP    (NL * 4)       // trace partial slots (17 blocks x 4 waves)

typedef float v4f __attribute__((ext_vector_type(4)));

// ---------------------------------------------------------------------------
// Kernel 1: expm of 4352 4x4 matrices (f32 scaling-and-squaring + Taylor-9).
// Per-wave trace partials to fixed slots (no atomic, no memset needed).
// ---------------------------------------------------------------------------
__global__ __launch_bounds__(256) void expm_kernel(const float* __restrict__ vs,
                                                   float* __restrict__ E,
                                                   float* __restrict__ tr_part) {
    const int m = blockIdx.x * 256 + threadIdx.x;   // 0..4351 (grid exact)
    const float* v = vs + (size_t)m * 16;
    float A[16], X[16], P[16], T[16];
    #pragma unroll
    for (int i = 0; i < 16; ++i) A[i] = v[i];
    const float tr = A[0] + A[5] + A[10] + A[15];

    float n1 = 0.0f;
    #pragma unroll
    for (int j = 0; j < 4; ++j) {
        float c = fabsf(A[j]) + fabsf(A[4 + j]) + fabsf(A[8 + j]) + fabsf(A[12 + j]);
        n1 = fmaxf(n1, c);
    }
    int s = 0;
    while (n1 > 0.25f && s < 30) { n1 *= 0.5f; ++s; }
    const float sc = __int_as_float((127 - s) << 23);   // 2^-s
    #pragma unroll
    for (int i = 0; i < 16; ++i) { A[i] *= sc; P[i] = A[i]; X[i] = A[i]; }
    X[0] += 1.0f; X[5] += 1.0f; X[10] += 1.0f; X[15] += 1.0f;

    #pragma unroll 1
    for (int k = 2; k <= 9; ++k) {
        const float invk = 1.0f / (float)k;
        #pragma unroll
        for (int i = 0; i < 4; ++i)
            #pragma unroll
            for (int j = 0; j < 4; ++j)
                T[i * 4 + j] = P[i * 4 + 0] * A[0 + j] + P[i * 4 + 1] * A[4 + j] +
                               P[i * 4 + 2] * A[8 + j] + P[i * 4 + 3] * A[12 + j];
        #pragma unroll
        for (int i = 0; i < 16; ++i) { P[i] = T[i] * invk; X[i] += P[i]; }
    }
    #pragma unroll 1
    for (int q = 0; q < s; ++q) {
        #pragma unroll
        for (int i = 0; i < 4; ++i)
            #pragma unroll
            for (int j = 0; j < 4; ++j)
                T[i * 4 + j] = X[i * 4 + 0] * X[0 + j] + X[i * 4 + 1] * X[4 + j] +
                               X[i * 4 + 2] * X[8 + j] + X[i * 4 + 3] * X[12 + j];
        #pragma unroll
        for (int i = 0; i < 16; ++i) X[i] = T[i];
    }
    float* e = E + (size_t)m * 16;
    #pragma unroll
    for (int i = 0; i < 16; ++i) e[i] = X[i];

    float tf = tr;
    #pragma unroll
    for (int off = 32; off > 0; off >>= 1) tf += __shfl_down(tf, off);
    if ((threadIdx.x & 63) == 0)
        tr_part[blockIdx.x * 4 + (threadIdx.x >> 6)] = tf;
}

// ---------------------------------------------------------------------------
// Kernel 2: fused 17-layer flow. 256 threads = 4 waves per block, RPB=8 rows.
// Thread t owns features 4t..4t+3 (one 4x4 block): b128 LDS staging writes at
// 16B lane stride are conflict-free. Gather uses one vaddr + folded row
// offsets (r*4096B fits the 16-bit DS offset). Bounded-ratio logdet:
// ratio = z/(2s)+1 in (0.5,1.5) -> product of 4 never overflows -> 1 log2
// per row-layer. No next-layer prefetch (that caused the R4 scratch spill).
// ---------------------------------------------------------------------------
__global__ __launch_bounds__(256, 4) void flow_kernel(const float* __restrict__ data,
                                                      const float* __restrict__ E,
                                                      const float* __restrict__ bs,
                                                      const int* __restrict__ idxs,
                                                      const float* __restrict__ tr_part,
                                                      float* __restrict__ out) {
    __shared__ float lds[RPB * IN_F];   // 32 KB
    __shared__ float red[RPB][4];
    const int t = threadIdx.x;
    const int row0 = blockIdx.x * RPB;

    v4f z[RPB];
    #pragma unroll
    for (int r = 0; r < RPB; ++r)
        z[r] = *(const v4f*)(data + (size_t)(row0 + r) * IN_F + 4 * t);

    float ld2[RPB];
    #pragma unroll
    for (int r = 0; r < RPB; ++r) ld2[r] = 0.0f;

    #pragma unroll 1
    for (int l = 0; l < NL; ++l) {
        if (l > 0) {
            // bent identity + logdet via bounded ratios (pk f32 math):
            //   inv = rsqrt(z^2+1); sq = (z^2+1)*inv = sqrt(z^2+1)
            //   ratio = 0.5*z*inv + 1 = z/(2s)+1  in (0.5, 1.5)
            //   z' = 0.5*sq + z - 0.5
            #pragma unroll
            for (int r = 0; r < RPB; ++r) {
                const v4f zz = z[r];
                const v4f q = zz * zz + 1.0f;
                v4f inv;
                inv.x = rsqrtf(q.x); inv.y = rsqrtf(q.y);
                inv.z = rsqrtf(q.z); inv.w = rsqrtf(q.w);
                const v4f sq = q * inv;                 // sqrt(z^2+1)
                const v4f rat = (0.5f * zz) * inv + 1.0f;
                z[r] = (0.5f * sq + zz) - 0.5f;
                ld2[r] += __log2f((rat.x * rat.y) * (rat.z * rat.w));
            }
        }

        // layer params (L2-resident: 16 KB E + 4 KB b + 4 KB idx per layer)
        const float* ep = E + ((size_t)l * NB + t) * 16;
        const v4f e0 = *(const v4f*)(ep + 0);
        const v4f e1 = *(const v4f*)(ep + 4);
        const v4f e2 = *(const v4f*)(ep + 8);
        const v4f e3 = *(const v4f*)(ep + 12);
        const v4f bv = *(const v4f*)(bs + (size_t)l * IN_F + 4 * t);
        const int4 id = *(const int4*)(idxs + (size_t)l * IN_F + 4 * t);

        // block-diag matvec + bias, staged to LDS (b128, conflict-free)
        #pragma unroll
        for (int r = 0; r < RPB; ++r) {
            const v4f zz = z[r];
            v4f y = bv;
            y += zz.x * e0;
            y += zz.y * e1;
            y += zz.z * e2;
            y += zz.w * e3;
            *(v4f*)(&lds[r * IN_F + 4 * t]) = y;
        }
        __syncthreads();

        // permutation gather: same idx for all rows -> one vaddr per element,
        // row handled by the folded offset immediate (r*4096 bytes)
        #pragma unroll
        for (int r = 0; r < RPB; ++r) {
            v4f zn;
            zn.x = lds[r * IN_F + id.x];
            zn.y = lds[r * IN_F + id.y];
            zn.z = lds[r * IN_F + id.z];
            zn.w = lds[r * IN_F + id.w];
            z[r] = zn;
        }
        __syncthreads();
    }

    // outputs
    float* out_z = out;
    float* out_ld = out + (size_t)BATCH_N * IN_F;
    #pragma unroll
    for (int r = 0; r < RPB; ++r)
        *(v4f*)(out_z + (size_t)(row0 + r) * IN_F + 4 * t) = z[r];

    // trace total (68 partials, L2-resident)
    float trs = 0.0f;
    const v4f* tp = (const v4f*)tr_part;
    #pragma unroll
    for (int i = 0; i < NL; ++i) {
        const v4f tv = tp[i];
        trs += (tv.x + tv.y) + (tv.z + tv.w);
    }

    // per-row logdet: wave shfl reduce, then cross-wave via LDS
    #pragma unroll
    for (int r = 0; r < RPB; ++r) {
        float p = ld2[r];
        #pragma unroll
        for (int off = 32; off > 0; off >>= 1) p += __shfl_down(p, off);
        if ((t & 63) == 0) red[r][t >> 6] = p;
    }
    __syncthreads();
    if (t < RPB) {
        const float ssum = red[t][0] + red[t][1] + red[t][2] + red[t][3];
        out_ld[row0 + t] = -trs - 0.6931471805599453f * ssum;
    }
}

// ---------------------------------------------------------------------------
extern "C" void kernel_launch(void* const* d_in, const int* in_sizes, int n_in,
                              void* d_out, int out_size, void* d_ws, size_t ws_size,
                              hipStream_t stream) {
    const float* data = (const float*)d_in[0];
    const float* vs   = (const float*)d_in[1];
    const float* bs   = (const float*)d_in[2];
    const int*   idxs = (const int*)d_in[3];

    float* ws      = (float*)d_ws;
    float* tr_part = ws;          // NTRP floats (all slots written by expm)
    float* E       = ws + 128;    // 17*256*16 floats = 272 KB

    expm_kernel<<<NL, 256, 0, stream>>>(vs, E, tr_part);
    flow_kernel<<<BATCH_N / RPB, 256, 0, stream>>>(data, E, bs, idxs, tr_part, (float*)d_out);
}